// Round 8
// baseline (238.518 us; speedup 1.0000x reference)
//
#include <hip/hip_runtime.h>
#include <cfloat>
#include <cstddef>

// VQ-VAE vector quantizer, MI355X / gfx950.
// z: (32, 64, 32, 32) f32 BCHW; embedding: (1024, 64) f32.
// Outputs concatenated f32: loss[1], z_q(BCHW)[2097152], perplexity[1],
// min_encodings[32768*1024], min_encoding_indices(as float)[32768].
//
// Structure history (measured):
//   R1 (108us): rows/lane, codes s_load, 8 DISJOINT streams/block -> sL1
//     thrash, VALU 37%.
//   R2 (284us): uniform-addr vector loads -> 64x RF replication.
//   R3 (154us): rows LDS-broadcast to 16 waves -> LDS return-bw bound.
//   R4 (181us): rows scalar-streamed at 4KB stride -> SMEM issue storm.
//   R5 (137us): quad-sliced codes -> reduction machinery 2x inst bloat.
//   R6 (199us): 4 codes/lane resident -> RF overflow + 1 wave/SIMD.
//   R7 (scan 91us, VALU 45%): scan/epilogue split, 4 shared scalar streams
//     per CU, 4 waves/SIMD TLP. Remaining stall: the every-32-codes
//     s_barrier CONVOYS the 4 sharing waves -> correlated misses, latency
//     taken in sync instead of pipelined. (SMEM returns are out-of-order on
//     CDNA: only lgkmcnt(0) is a safe wait, so s_load double-buffering at
//     source level is impossible -- decorrelated TLP is the only
//     latency-hiding mechanism for the scalar path.)
//   R8 (this): R7 minus the barriers, plus per-wave staggered start offsets
//     (rg*32 within the 128-code chunk, wrap-around) so sharing waves are
//     always on different lines; explicit (d,j) tie-break restores exact
//     first-index argmin under the rotated scan order.
//
// Numerics (must match the absmax-0.0 lineage bit-for-bit):
//   dot: 4 fp32 fma chains m=c%4 over k ascending, final (a0+a1)+(a2+a3);
//     v2f elementwise_fma packs chains (a0,a1),(a2,a3) -- identical
//     per-element rounding, proven exact R2-R7.
//   e2/z2: sequential double accumulation (ch ascending), rounded once
//     (e2 in a pre-kernel, proven R5/R7; z2 from the row regs, c ascending).
//   d = (z2f + e2f) - 2.0f*dot (two fp32 roundings at magnitude ~64).
//   argmin: explicit (d < bd) || (d == bd && j < bj) update is
//     order-independent and equals np.argmin first-index; epilogue combines
//     the 8 chunk-candidates in ascending-chunk order with strict <.
//   loss: epilogue reproduces R1's partial[512] tree verbatim; vq_final
//     unchanged.

#define NROWS 32768
#define NE    1024
#define EDIM  64
#define TPB_A 512
#define GRID_A 512            // 128 row-blocks x 4 code-blocks
#define TPB_B 256
#define GRID_B 512            // 64 rows each
#define NPART 512

#define OFF_LOSS ((size_t)0)
#define OFF_ZQ   ((size_t)1)
#define OFF_PERP ((size_t)2097153)
#define OFF_OH   ((size_t)2097154)
#define OFF_IDX  ((size_t)35651586)

typedef float v2f __attribute__((ext_vector_type(2)));

// ws layout (bytes): [0,4096) int hist[1024]; [4096,6144) float partial[512];
//                    [8192,12288) float e2buf[1024]

__global__ __launch_bounds__(128) void vq_e2(const float* __restrict__ emb,
                                             float* __restrict__ e2buf) {
    int j = blockIdx.x * 128 + threadIdx.x;          // grid 8x128 = 1024
    const float* e = emb + ((size_t)j << 6);
    double s = 0.0;
#pragma unroll
    for (int c = 0; c < EDIM; ++c) { float v = e[c]; s += (double)v * (double)v; }
    e2buf[j] = (float)s;
}

__global__ __launch_bounds__(TPB_A, 4) void vq_scan(const float* __restrict__ z,
                                                    const float* __restrict__ emb,
                                                    const float* __restrict__ e2buf,
                                                    float* __restrict__ out) {
    const int t    = threadIdx.x;
    const int lane = t & 63;
    const int q    = t >> 6;                 // wave 0..7
    const int rb   = blockIdx.x >> 2;        // row-block 0..127
    const int cb   = blockIdx.x & 3;         // code-block 0..3
    const int r0   = rb << 8;                // 256 rows per block
    const int rg   = q & 3;                  // row group within block
    // hf selects the wave's 128-code half; readfirstlane makes it provably
    // wave-uniform so the codebook loads compile to s_load (R1/R7-proven).
    const int hf   = __builtin_amdgcn_readfirstlane(q >> 2);
    // staggered start offset within the chunk: the 4 waves sharing a chunk
    // (rg = 0..3) begin 32 codes apart -> decorrelated misses, latencies
    // pipelined by TLP instead of taken in sync.
    const int s0   = __builtin_amdgcn_readfirstlane((q & 3) << 5);

    const int row  = r0 + (rg << 6) + lane;
    const int b    = row >> 10;
    const int m    = row & 1023;
    const size_t zbase = (size_t)b * 65536 + (size_t)m;

    // ---- this lane's z row (64 ch, stride 1024) + ||z||^2 -----------------
    v2f zp[32];
    double sd = 0.0;
#pragma unroll
    for (int n = 0; n < 32; ++n) {
        float x = z[zbase + (size_t)(2 * n) * 1024];
        float y = z[zbase + (size_t)(2 * n + 1) * 1024];
        zp[n] = (v2f){x, y};
        sd += (double)x * (double)x;         // c ascending: 2n then 2n+1
        sd += (double)y * (double)y;
    }
    const float z2f = (float)sd;

    // ---- fire-and-forget zero-fill: this block's one-hot column chunk ----
    // rows [r0, r0+256) x cols [cb*256, +256) = 256 KB. float2 (8B-aligned;
    // OFF_OH is even). The scan below is SMEM/VALU only with NO waits on
    // vmem -> these stores drain under the scan.
    {
        float* basep = out + OFF_OH + (size_t)r0 * 1024 + (cb << 8);
        for (int i = t; i < 32768; i += TPB_A) {
            int r  = i >> 7;                 // 0..255
            int c2 = i & 127;                // float2 column
            *(float2*)(basep + (size_t)r * 1024 + 2 * c2) = make_float2(0.f, 0.f);
        }
    }

    // ---- scan this wave's 128 codes via shared scalar stream --------------
    // All 4 waves with the same (cb,hf) on a CU stream the SAME contiguous
    // 32KB codebook chunk, but at staggered phases (no barriers): each
    // wave's ~200cyc L2 latency hides under the other three's compute.
    const int jf = (cb << 8) + (hf << 7);
    float bestd = FLT_MAX;
    int   bestj = NE;
    for (int ii = 0; ii < 128; ++ii) {
        const int jj = (ii + s0) & 127;      // rotated scan order
        const int j  = jf + jj;
        const float4* ep = (const float4*)(emb + ((size_t)j << 6));
        const float e2f = e2buf[j];          // s_load (uniform)
        float4 e[16];
#pragma unroll
        for (int k = 0; k < 16; ++k) e[k] = ep[k];   // s_load_dwordx16 x4
        v2f a01 = {0.f, 0.f}, a23 = {0.f, 0.f};
#pragma unroll
        for (int k = 0; k < 16; ++k) {
            v2f exy = {e[k].x, e[k].y};
            v2f ezw = {e[k].z, e[k].w};
            a01 = __builtin_elementwise_fma(exy, zp[2 * k],     a01);
            a23 = __builtin_elementwise_fma(ezw, zp[2 * k + 1], a23);
        }
        float dot = (a01.x + a01.y) + (a23.x + a23.y);
        float d   = (z2f + e2f) - 2.0f * dot;
        // order-independent first-index argmin (scan order is rotated)
        if (d < bestd || (d == bestd && j < bestj)) { bestd = d; bestj = j; }
    }

    // ---- stash candidate (d, j) in the z_q region, channels 2gc, 2gc+1 ----
    // The epilogue kernel reads these for its rows BEFORE overwriting the
    // region with z_q (kernel boundary orders scan-writes vs epi-reads).
    const int gc = (cb << 1) + hf;           // global chunk 0..7, ascending j
    out[OFF_ZQ + zbase + (size_t)(2 * gc) * 1024]     = bestd;
    out[OFF_ZQ + zbase + (size_t)(2 * gc + 1) * 1024] = __int_as_float(bestj);
}

__global__ __launch_bounds__(TPB_B) void vq_epi(const float* __restrict__ z,
                                                const float* __restrict__ emb,
                                                int* __restrict__ hist,
                                                float* __restrict__ partial,
                                                float* __restrict__ out) {
    const int t    = threadIdx.x;
    const int lane = t & 63;
    const int q    = t >> 6;                 // wave 0..3
    const int r0   = blockIdx.x << 6;        // 64 rows per block

    __shared__ int   s_idx[64];
    __shared__ float s_l[8];

    // ---- combine 8 chunk candidates per row (ascending chunk = ascending
    //      code range; strict < keeps the first/lowest index) --------------
    if (t < 64) {
        const int row = r0 + t;
        const int b   = row >> 10;
        const int m   = row & 1023;
        const size_t zbase = (size_t)b * 65536 + (size_t)m;
        const float* cp = out + OFF_ZQ + zbase;
        float bd = cp[0];
        int   bj = __float_as_int(cp[1024]);
#pragma unroll
        for (int gc = 1; gc < 8; ++gc) {
            float d = cp[(size_t)(2 * gc) * 1024];
            int   j = __float_as_int(cp[(size_t)(2 * gc + 1) * 1024]);
            if (d < bd) { bd = d; bj = j; }
        }
        s_idx[t] = bj;
        out[OFF_IDX + row] = (float)bj;                       // index as float
        out[OFF_OH + (size_t)row * 1024 + bj] = 1.0f;         // one-hot scatter
        atomicAdd(&hist[bj], 1);
    }
    __syncthreads();   // candidates of ALL rows read before z_q overwrites

    // ---- z_q (straight-through) + loss partial: R1's tree verbatim -------
    // wave q handles classes {q, q+4}; chains c = cls + 8i (i ascending),
    // shfl_down butterfly, s_l[8] summed ascending -> partial[512]
    // bit-identical to the R1 lineage; vq_final unchanged.
    {
        const int row = r0 + lane;
        const int b   = row >> 10;
        const int m   = row & 1023;
        const size_t zbr = (size_t)b * 65536 + (size_t)m;
        const int    jjx = s_idx[lane];
        const float* er  = emb + ((size_t)jjx << 6);
        float* zq = out + OFF_ZQ + zbr;
#pragma unroll
        for (int p = 0; p < 2; ++p) {
            const int cls = q + 4 * p;
            float ls = 0.f;
#pragma unroll
            for (int i = 0; i < 8; ++i) {
                int c = cls + 8 * i;
                float zc   = z[zbr + (size_t)c * 1024];       // coalesced
                float ev   = er[c];                           // gather (L2)
                float diff = ev - zc;
                zq[(size_t)c * 1024] = zc + diff;             // zp + (z_q-zp)
                ls = fmaf(diff, diff, ls);
            }
#pragma unroll
            for (int off = 32; off >= 1; off >>= 1) ls += __shfl_down(ls, off);
            if (lane == 0) s_l[cls] = ls;
        }
        __syncthreads();
        if (t == 0) {
            float l = 0.f;
#pragma unroll
            for (int c = 0; c < 8; ++c) l += s_l[c];          // ascending
            partial[blockIdx.x] = l;
        }
    }
}

__global__ __launch_bounds__(1024) void vq_final(const int* __restrict__ hist,
                                                 const float* __restrict__ partial,
                                                 float* __restrict__ out) {
    int t = threadIdx.x;
    float p    = (float)hist[t] * (1.0f / 32768.0f);
    float term = p * logf(p + 1e-10f);
    float lp   = (t < NPART) ? partial[t] : 0.f;
#pragma unroll
    for (int off = 32; off >= 1; off >>= 1) {
        term += __shfl_down(term, off);
        lp   += __shfl_down(lp, off);
    }
    __shared__ float st[16], sl[16];
    int w = t >> 6, ln = t & 63;
    if (ln == 0) { st[w] = term; sl[w] = lp; }
    __syncthreads();
    if (t == 0) {
        float s = 0.f, l = 0.f;
#pragma unroll
        for (int i = 0; i < 16; ++i) { s += st[i]; l += sl[i]; }
        out[OFF_LOSS] = 1.25f * l * (1.0f / 2097152.0f);  // (1+beta)*mean
        out[OFF_PERP] = expf(-s);
    }
}

extern "C" void kernel_launch(void* const* d_in, const int* in_sizes, int n_in,
                              void* d_out, int out_size, void* d_ws, size_t ws_size,
                              hipStream_t stream) {
    const float* z   = (const float*)d_in[0];
    const float* emb = (const float*)d_in[1];
    float* out     = (float*)d_out;
    int*   hist    = (int*)d_ws;
    float* partial = (float*)((char*)d_ws + 4096);
    float* e2buf   = (float*)((char*)d_ws + 8192);

    hipMemsetAsync(hist, 0, 4096, stream);
    vq_e2<<<8, 128, 0, stream>>>(emb, e2buf);
    vq_scan<<<GRID_A, TPB_A, 0, stream>>>(z, emb, e2buf, out);
    vq_epi<<<GRID_B, TPB_B, 0, stream>>>(z, emb, hist, partial, out);
    vq_final<<<1, 1024, 0, stream>>>(hist, partial, out);
}

// Round 9
// 211.257 us; speedup vs baseline: 1.1290x; 1.1290x over previous
//
#include <hip/hip_runtime.h>
#include <cfloat>
#include <cstddef>

// VQ-VAE vector quantizer, MI355X / gfx950.
// z: (32, 64, 32, 32) f32 BCHW; embedding: (1024, 64) f32.
// Outputs concatenated f32: loss[1], z_q(BCHW)[2097152], perplexity[1],
// min_encodings[32768*1024], min_encoding_indices(as float)[32768].
//
// Structure history (measured):
//   R1 (108us): rows/lane, codes s_load, disjoint streams -> VALU 37%.
//   R2 (284us): uniform-addr vector loads -> 64x RF replication.
//   R3 (154us): rows LDS-broadcast to 16 waves -> LDS return-bw bound.
//   R4 (181us): rows scalar-streamed at 4KB stride -> SMEM issue storm.
//   R5 (137us): quad-sliced codes -> reduction machinery 2x inst bloat.
//   R6 (199us): 4 codes/lane resident -> RF overflow + 1 wave/SIMD.
//   R7 (scan 91us, VALU 45%): scan/epi split, shared scalar streams,
//     4 waves/SIMD.
//   R8 (scan 102us): stagger broke sL1 sharing -> FETCH +8MB, worse.
//   DIAGNOSIS that fits all data: per code a wave issues ~150cyc VALU vs
//     ~300cyc exposed SMEM latency (SGPR budget 102 < 2x64 -> no double
//     buffering possible, structural). Duty/wave ~33%; at 4 waves/SIMD
//     -> ~45% VALUBusy == measured. Fix = MORE WAVES, not smarter streams.
//   R9 (this): same inner loop, occupancy 2.5x: grid 2048 (512 row-blocks
//     x 4 code-blocks), TPB 256 (4 waves; lane=row, wave q scans 64 codes),
//     launch_bounds(256,5) -> ~80 VGPR, 5 blocks/CU = 5 waves/SIMD ->
//     duty 5x33% -> VALU-saturated. Ascending scan, no barriers, no
//     stagger. Zero-fill interleaved into the scan (1 float2 store per 2
//     codes; ordering vs the 1.0 scatter is by KERNEL BOUNDARY). In-block
//     combine cuts candidate stash 4x (1 per row per code-block).
//
// Numerics (must match the absmax-0.0 lineage bit-for-bit):
//   dot: 4 fp32 fma chains m=c%4 over k ascending, final (a0+a1)+(a2+a3);
//     v2f elementwise_fma packs chains (a0,a1),(a2,a3) -- identical
//     per-element rounding, proven exact R2-R8.
//   e2/z2: sequential double accumulation (ch ascending), rounded once
//     (e2 in a pre-kernel, proven R5/R7/R8; z2 from row regs, c ascending).
//   d = (z2f + e2f) - 2.0f*dot (two fp32 roundings at magnitude ~64).
//   argmin: wave scans its 64 codes ascending with strict < (first index);
//     in-block combine over waves q=0..3 ascending (ascending j ranges,
//     strict <); epilogue combines the 4 code-block candidates in
//     ascending-cb order with strict < -> exact np.argmin first-index.
//   loss: epilogue reproduces R1's partial[512] tree verbatim; vq_final
//     unchanged.

#define NROWS 32768
#define NE    1024
#define EDIM  64
#define TPB_A 256
#define GRID_A 2048           // 512 row-blocks x 4 code-blocks
#define TPB_B 256
#define GRID_B 512            // 64 rows each
#define NPART 512

#define OFF_LOSS ((size_t)0)
#define OFF_ZQ   ((size_t)1)
#define OFF_PERP ((size_t)2097153)
#define OFF_OH   ((size_t)2097154)
#define OFF_IDX  ((size_t)35651586)

typedef float v2f __attribute__((ext_vector_type(2)));

// ws layout (bytes): [0,4096) int hist[1024]; [4096,6144) float partial[512];
//                    [8192,12288) float e2buf[1024]

__global__ __launch_bounds__(128) void vq_e2(const float* __restrict__ emb,
                                             float* __restrict__ e2buf) {
    int j = blockIdx.x * 128 + threadIdx.x;          // grid 8x128 = 1024
    const float* e = emb + ((size_t)j << 6);
    double s = 0.0;
#pragma unroll
    for (int c = 0; c < EDIM; ++c) { float v = e[c]; s += (double)v * (double)v; }
    e2buf[j] = (float)s;
}

__global__ __launch_bounds__(TPB_A, 5) void vq_scan(const float* __restrict__ z,
                                                    const float* __restrict__ emb,
                                                    const float* __restrict__ e2buf,
                                                    float* __restrict__ out) {
    const int t    = threadIdx.x;
    const int lane = t & 63;
    const int q    = t >> 6;                 // wave 0..3
    const int rb   = blockIdx.x >> 2;        // row-block 0..511
    const int cb   = blockIdx.x & 3;         // code-block 0..3
    const int r0   = rb << 6;                // 64 rows per block
    // readfirstlane: provably wave-uniform -> codebook loads stay SCALAR
    // (s_load); without it divergence analysis sees q as divergent and
    // emits vector loads (R2's 64x replication disaster).
    const int qu   = __builtin_amdgcn_readfirstlane(q);

    const int row  = r0 + lane;              // lane owns this row
    const int b    = row >> 10;
    const int m    = row & 1023;
    const size_t zbase = (size_t)b * 65536 + (size_t)m;

    __shared__ float s_wd[4][64];
    __shared__ int   s_wj[4][64];

    // ---- this lane's z row (64 ch, stride 1024) + ||z||^2 -----------------
    v2f zp[32];
    double sd = 0.0;
#pragma unroll
    for (int n = 0; n < 32; ++n) {
        float x = z[zbase + (size_t)(2 * n) * 1024];
        float y = z[zbase + (size_t)(2 * n + 1) * 1024];
        zp[n] = (v2f){x, y};
        sd += (double)x * (double)x;         // c ascending: 2n then 2n+1
        sd += (double)y * (double)y;
    }
    const float z2f = (float)sd;             // consumes loads -> vmcnt drains

    // zero-fill slab: one-hot rows [r0,+64) x cols [256*cb, +256) = 64 KB.
    // Issued INSIDE the scan loop (1 float2 store per 2 codes, 32/thread):
    // vmem queue stays shallow, stores drain to HBM under the compute, and
    // the 1.0f scatter in vq_epi is ordered after them by the KERNEL
    // BOUNDARY (stronger than the old in-kernel barrier trick).
    float* ohb = out + OFF_OH + (size_t)r0 * 1024 + (cb << 8);  // 8B-aligned

    // ---- scan this wave's 64 codes via scalar stream ----------------------
    // 20 waves/CU (5 blocks x 4 waves) = 5 waves/SIMD: per-wave duty ~33%
    // (150cyc VALU vs ~300cyc SMEM latency, no SGPR double-buffer possible)
    // x5 -> VALU-saturated. No barriers, no stagger: TLP hides latency
    // regardless of sL1 hit rate; stream bandwidth is trivial.
    const int jf = (cb << 8) + (qu << 6);
    float bestd = FLT_MAX;
    int   bestj = 0;
    for (int jj = 0; jj < 64; ++jj) {
        if (!(jj & 1)) {
            int i  = t + (jj >> 1) * TPB_A;  // 0..8191
            int r  = i >> 7;                 // 0..63
            int c2 = i & 127;                // float2 column within 256 cols
            *(float2*)(ohb + (size_t)r * 1024 + 2 * c2) = make_float2(0.f, 0.f);
        }
        const int j = jf + jj;
        const float4* ep = (const float4*)(emb + ((size_t)j << 6));
        const float e2f = e2buf[j];          // s_load (uniform)
        float4 e[16];
#pragma unroll
        for (int k = 0; k < 16; ++k) e[k] = ep[k];   // s_load_dwordx16 x4
        v2f a01 = {0.f, 0.f}, a23 = {0.f, 0.f};
#pragma unroll
        for (int k = 0; k < 16; ++k) {
            v2f exy = {e[k].x, e[k].y};
            v2f ezw = {e[k].z, e[k].w};
            a01 = __builtin_elementwise_fma(exy, zp[2 * k],     a01);
            a23 = __builtin_elementwise_fma(ezw, zp[2 * k + 1], a23);
        }
        float dot = (a01.x + a01.y) + (a23.x + a23.y);
        float d   = (z2f + e2f) - 2.0f * dot;
        if (d < bestd) { bestd = d; bestj = j; }     // ascending: first index
    }

    // ---- in-block combine over 4 waves (ascending j ranges, strict <) ----
    s_wd[q][lane] = bestd;
    s_wj[q][lane] = bestj;
    __syncthreads();
    if (t < 64) {
        float bd = s_wd[0][t];
        int   bj = s_wj[0][t];
#pragma unroll
        for (int w = 1; w < 4; ++w) {
            float dw = s_wd[w][t];
            if (dw < bd) { bd = dw; bj = s_wj[w][t]; }
        }
        // stash (d, j) in the z_q region, channels 2cb / 2cb+1 (0..7);
        // vq_epi reads these BEFORE overwriting the region with z_q.
        const int rr = r0 + t;
        const size_t zb2 = (size_t)(rr >> 10) * 65536 + (size_t)(rr & 1023);
        out[OFF_ZQ + zb2 + (size_t)(2 * cb) * 1024]     = bd;
        out[OFF_ZQ + zb2 + (size_t)(2 * cb + 1) * 1024] = __int_as_float(bj);
    }
}

__global__ __launch_bounds__(TPB_B) void vq_epi(const float* __restrict__ z,
                                                const float* __restrict__ emb,
                                                int* __restrict__ hist,
                                                float* __restrict__ partial,
                                                float* __restrict__ out) {
    const int t    = threadIdx.x;
    const int lane = t & 63;
    const int q    = t >> 6;                 // wave 0..3
    const int r0   = blockIdx.x << 6;        // 64 rows per block

    __shared__ int   s_idx[64];
    __shared__ float s_l[8];

    // ---- combine 4 code-block candidates per row (ascending cb = ascending
    //      code range; strict < keeps the first/lowest index) --------------
    if (t < 64) {
        const int row = r0 + t;
        const int b   = row >> 10;
        const int m   = row & 1023;
        const size_t zbase = (size_t)b * 65536 + (size_t)m;
        const float* cp = out + OFF_ZQ + zbase;
        float bd = cp[0];
        int   bj = __float_as_int(cp[1024]);
#pragma unroll
        for (int gc = 1; gc < 4; ++gc) {
            float d = cp[(size_t)(2 * gc) * 1024];
            int   j = __float_as_int(cp[(size_t)(2 * gc + 1) * 1024]);
            if (d < bd) { bd = d; bj = j; }
        }
        s_idx[t] = bj;
        out[OFF_IDX + row] = (float)bj;                       // index as float
        out[OFF_OH + (size_t)row * 1024 + bj] = 1.0f;         // one-hot scatter
        atomicAdd(&hist[bj], 1);
    }
    __syncthreads();   // candidates of ALL rows read before z_q overwrites

    // ---- z_q (straight-through) + loss partial: R1's tree verbatim -------
    // wave q handles classes {q, q+4}; chains c = cls + 8i (i ascending),
    // shfl_down butterfly, s_l[8] summed ascending -> partial[512]
    // bit-identical to the R1 lineage; vq_final unchanged.
    {
        const int row = r0 + lane;
        const int b   = row >> 10;
        const int m   = row & 1023;
        const size_t zbr = (size_t)b * 65536 + (size_t)m;
        const int    jjx = s_idx[lane];
        const float* er  = emb + ((size_t)jjx << 6);
        float* zq = out + OFF_ZQ + zbr;
#pragma unroll
        for (int p = 0; p < 2; ++p) {
            const int cls = q + 4 * p;
            float ls = 0.f;
#pragma unroll
            for (int i = 0; i < 8; ++i) {
                int c = cls + 8 * i;
                float zc   = z[zbr + (size_t)c * 1024];       // coalesced
                float ev   = er[c];                           // gather (L2)
                float diff = ev - zc;
                zq[(size_t)c * 1024] = zc + diff;             // zp + (z_q-zp)
                ls = fmaf(diff, diff, ls);
            }
#pragma unroll
            for (int off = 32; off >= 1; off >>= 1) ls += __shfl_down(ls, off);
            if (lane == 0) s_l[cls] = ls;
        }
        __syncthreads();
        if (t == 0) {
            float l = 0.f;
#pragma unroll
            for (int c = 0; c < 8; ++c) l += s_l[c];          // ascending
            partial[blockIdx.x] = l;
        }
    }
}

__global__ __launch_bounds__(1024) void vq_final(const int* __restrict__ hist,
                                                 const float* __restrict__ partial,
                                                 float* __restrict__ out) {
    int t = threadIdx.x;
    float p    = (float)hist[t] * (1.0f / 32768.0f);
    float term = p * logf(p + 1e-10f);
    float lp   = (t < NPART) ? partial[t] : 0.f;
#pragma unroll
    for (int off = 32; off >= 1; off >>= 1) {
        term += __shfl_down(term, off);
        lp   += __shfl_down(lp, off);
    }
    __shared__ float st[16], sl[16];
    int w = t >> 6, ln = t & 63;
    if (ln == 0) { st[w] = term; sl[w] = lp; }
    __syncthreads();
    if (t == 0) {
        float s = 0.f, l = 0.f;
#pragma unroll
        for (int i = 0; i < 16; ++i) { s += st[i]; l += sl[i]; }
        out[OFF_LOSS] = 1.25f * l * (1.0f / 2097152.0f);  // (1+beta)*mean
        out[OFF_PERP] = expf(-s);
    }
}

extern "C" void kernel_launch(void* const* d_in, const int* in_sizes, int n_in,
                              void* d_out, int out_size, void* d_ws, size_t ws_size,
                              hipStream_t stream) {
    const float* z   = (const float*)d_in[0];
    const float* emb = (const float*)d_in[1];
    float* out     = (float*)d_out;
    int*   hist    = (int*)d_ws;
    float* partial = (float*)((char*)d_ws + 4096);
    float* e2buf   = (float*)((char*)d_ws + 8192);

    hipMemsetAsync(hist, 0, 4096, stream);
    vq_e2<<<8, 128, 0, stream>>>(emb, e2buf);
    vq_scan<<<GRID_A, TPB_A, 0, stream>>>(z, emb, e2buf, out);
    vq_epi<<<GRID_B, TPB_B, 0, stream>>>(z, emb, hist, partial, out);
    vq_final<<<1, 1024, 0, stream>>>(hist, partial, out);
}